// Round 1
// baseline (325.820 us; speedup 1.0000x reference)
//
#include <hip/hip_runtime.h>
#include <math.h>

#define LP 800
#define DP 200
#define HP 100
#define PP 128
#define KP 2
#define MP 256   // PP*KP
#define MM1 255

// d_out offsets (in floats), reference return order
#define OFF_SCS  0u
#define OFF_R    40960000u
#define OFF_ENC  40985600u
#define OFF_V    41190400u
#define OFF_TIL  41255680u

// workspace offsets (in floats)
#define WS_C     0u
#define WS_O     25600u
#define WS_E     51200u
#define WS_ALPHA 116480u
#define WS_COLA  181760u

// ---------------- Kernel A: S_Cs masked stream copy (float4) ----------------
// S_Cs[m] flat = S_p[p] flat where t in [start,end], else 0. Per-m image is
// 800*200 = 160000 floats = 40000 float4. grid = (157, 256), block = 256.
__global__ void scs_kernel(const float4* __restrict__ Sp4,
                           const int* __restrict__ spans,
                           float4* __restrict__ out4) {
    int m = blockIdx.y;
    int off = blockIdx.x * blockDim.x + threadIdx.x;
    if (off >= 40000) return;
    int p = m >> 1, k = m & 1;
    int start = spans[p * 4 + k * 2];
    int end   = spans[p * 4 + k * 2 + 1];
    int t = off / 50;   // 50 float4 per D-row
    float4 v = make_float4(0.f, 0.f, 0.f, 0.f);
    if (t >= start && t <= end) v = Sp4[p * 40000 + off];
    out4[m * 40000 + off] = v;
}

// ---------------- Kernel B: encoded_candidates (as float) ----------------
__global__ void enc_kernel(const int* __restrict__ passages,
                           const int* __restrict__ spans,
                           float* __restrict__ enc) {
    int m = blockIdx.x;
    int p = m >> 1, k = m & 1;
    int start = spans[p * 4 + k * 2];
    int end   = spans[p * 4 + k * 2 + 1];
    int len = end - start;
    for (int t = threadIdx.x; t < LP; t += blockDim.x) {
        int g = start + t; if (g > LP - 1) g = LP - 1;
        int tok = (t <= len) ? passages[p * LP + g] : 0;
        enc[m * LP + t] = (float)tok;
    }
}

// ---------------- Kernel C: r_Cs, c, o (one block per m) ----------------
__global__ void rco_kernel(const float* __restrict__ Sp,
                           const int* __restrict__ spans,
                           const float* __restrict__ Wb,
                           const float* __restrict__ We,
                           const float* __restrict__ Wc,
                           const float* __restrict__ Wo,
                           float* __restrict__ r_out,
                           float* __restrict__ c_ws,
                           float* __restrict__ o_ws) {
    __shared__ float sb[DP], se[DP], rs[HP];
    int m = blockIdx.x;
    int p = m >> 1, k = m & 1;
    int start = spans[p * 4 + k * 2];
    int end   = spans[p * 4 + k * 2 + 1];
    const float* sbp = Sp + (size_t)(p * LP + start) * DP;
    const float* sep = Sp + (size_t)(p * LP + end) * DP;
    for (int d = threadIdx.x; d < DP; d += blockDim.x) {
        sb[d] = sbp[d];
        se[d] = sep[d];
    }
    __syncthreads();
    int h = threadIdx.x;
    if (h < HP) {
        const float* wb = Wb + h * DP;
        const float* we = We + h * DP;
        float acc = 0.f;
        for (int d = 0; d < DP; ++d) acc += sb[d] * wb[d] + se[d] * we[d];
        float r = tanhf(acc);
        rs[h] = r;
        r_out[m * HP + h] = r;
    }
    __syncthreads();
    if (h < HP) {
        const float* wc = Wc + h * HP;
        const float* wo = Wo + h * HP;
        float accc = 0.f, acco = 0.f;
        for (int hp = 0; hp < HP; ++hp) {
            float r = rs[hp];
            accc += r * wc[hp];
            acco += r * wo[hp];
        }
        c_ws[m * HP + h] = accc;
        o_ws[m * HP + h] = acco;
    }
}

// ---------------- Kernel D: V (diag removed) + E = exp(V) ----------------
// one block per row i, thread j' in [0,255) handles V[i][j'], j = j' + (j'>=i)
__global__ void v_kernel(const float* __restrict__ c_ws,
                         const float* __restrict__ o_ws,
                         const float* __restrict__ Wv,
                         float* __restrict__ V_out,
                         float* __restrict__ E_ws) {
    __shared__ float cs[HP], wv[HP];
    int i = blockIdx.x;
    if (threadIdx.x < HP) {
        cs[threadIdx.x] = c_ws[i * HP + threadIdx.x];
        wv[threadIdx.x] = Wv[threadIdx.x];
    }
    __syncthreads();
    int jp = threadIdx.x;
    if (jp < MM1) {
        int j = jp + (jp >= i ? 1 : 0);
        const float* oj = o_ws + j * HP;
        float acc = 0.f;
        for (int h = 0; h < HP; ++h) acc += tanhf(cs[h] + oj[h]) * wv[h];
        V_out[i * MM1 + jp] = acc;
        E_ws[i * MM1 + jp] = expf(acc);
    }
}

// ---------------- Kernel E: column sums -> alpha -> colA (single block) ----------------
__global__ void alpha_kernel(const float* __restrict__ E_ws,
                             float* __restrict__ alpha_ws,
                             float* __restrict__ colA_ws) {
    int jp = threadIdx.x;
    if (jp >= MM1) return;
    float colE = 0.f;
    for (int i = 0; i < MP; ++i) colE += E_ws[i * MM1 + jp];
    float colA = 0.f;
    for (int i = 0; i < MP; ++i) {
        float e = E_ws[i * MM1 + jp];
        float a = e / (colE - e);
        alpha_ws[i * MM1 + jp] = a;
        colA += a;
    }
    colA_ws[jp] = colA;
}

// ---------------- Kernel F: tilda_r_Cs ----------------
// one block per m=i; s_rows[i][j'] = colA[j'] - alpha[i][j'];
// tilda[i][h] = sum_j' s[j'] * r_Cs[j][h], j = j' + (j'>=i)
__global__ void tilda_kernel(const float* __restrict__ alpha_ws,
                             const float* __restrict__ colA_ws,
                             const float* __restrict__ r_out,
                             float* __restrict__ til_out) {
    __shared__ float s[MM1];
    int i = blockIdx.x;
    for (int jp = threadIdx.x; jp < MM1; jp += blockDim.x)
        s[jp] = colA_ws[jp] - alpha_ws[i * MM1 + jp];
    __syncthreads();
    int h = threadIdx.x;
    if (h < HP) {
        float acc = 0.f;
        for (int jp = 0; jp < MM1; ++jp) {
            int j = jp + (jp >= i ? 1 : 0);
            acc += s[jp] * r_out[j * HP + h];
        }
        til_out[i * HP + h] = acc;
    }
}

extern "C" void kernel_launch(void* const* d_in, const int* in_sizes, int n_in,
                              void* d_out, int out_size, void* d_ws, size_t ws_size,
                              hipStream_t stream) {
    const float* S_p      = (const float*)d_in[0];
    const int*   spans    = (const int*)d_in[1];
    const int*   passages = (const int*)d_in[2];
    const float* Wb       = (const float*)d_in[3];
    const float* We       = (const float*)d_in[4];
    const float* Wc       = (const float*)d_in[5];
    const float* Wo       = (const float*)d_in[6];
    const float* Wv       = (const float*)d_in[7];

    float* out = (float*)d_out;
    float* ws  = (float*)d_ws;

    float* out_scs = out + OFF_SCS;
    float* out_r   = out + OFF_R;
    float* out_enc = out + OFF_ENC;
    float* out_v   = out + OFF_V;
    float* out_til = out + OFF_TIL;

    float* ws_c     = ws + WS_C;
    float* ws_o     = ws + WS_O;
    float* ws_e     = ws + WS_E;
    float* ws_alpha = ws + WS_ALPHA;
    float* ws_colA  = ws + WS_COLA;

    // A: big masked stream copy (dominant, HBM-bound)
    dim3 gridA((40000 + 255) / 256, MP);
    scs_kernel<<<gridA, 256, 0, stream>>>((const float4*)S_p, spans, (float4*)out_scs);

    // B: encoded candidates
    enc_kernel<<<MP, 256, 0, stream>>>(passages, spans, out_enc);

    // C: r_Cs + c + o
    rco_kernel<<<MP, 128, 0, stream>>>(S_p, spans, Wb, We, Wc, Wo, out_r, ws_c, ws_o);

    // D: V + E
    v_kernel<<<MP, 256, 0, stream>>>(ws_c, ws_o, Wv, out_v, ws_e);

    // E: alpha + colA (single block)
    alpha_kernel<<<1, 256, 0, stream>>>(ws_e, ws_alpha, ws_colA);

    // F: tilda_r_Cs
    tilda_kernel<<<MP, 128, 0, stream>>>(ws_alpha, ws_colA, out_r, out_til);
}

// Round 3
// 277.382 us; speedup vs baseline: 1.1746x; 1.1746x over previous
//
#include <hip/hip_runtime.h>
#include <math.h>

#define LP 800
#define DP 200
#define HP 100
#define MP 256   // P*K
#define MM1 255

typedef float fx4 __attribute__((ext_vector_type(4)));

// d_out offsets (floats), reference return order
#define OFF_SCS  0u
#define OFF_R    40960000u
#define OFF_ENC  40985600u
#define OFF_V    41190400u
#define OFF_TIL  41255680u

// workspace offsets (floats)
#define WS_C     0u        // 25600
#define WS_O     25600u    // 25600
#define WS_E     51200u    // 65280
#define WS_S     116480u   // 65280  (s_rows, row-major [i][jp])

__device__ __forceinline__ float tanh_fast(float x) {
    // tanh(x) = 1 - 2/(exp(2x)+1); exact at both saturation ends.
    float e = __expf(2.0f * x);
    return 1.0f - 2.0f / (e + 1.0f);
}

// ---------------- Kernel A: S_Cs masked stream copy (fx4, NT stores) ----
__global__ __launch_bounds__(256) void scs_kernel(const fx4* __restrict__ Sp4,
                                                  const int* __restrict__ spans,
                                                  fx4* __restrict__ out4) {
    int m = blockIdx.y;
    int off = blockIdx.x * blockDim.x + threadIdx.x;
    if (off >= 40000) return;
    int p = m >> 1, k = m & 1;
    int start = spans[p * 4 + k * 2];
    int end   = spans[p * 4 + k * 2 + 1];
    int t = off / 50;   // 50 fx4 per D-row
    fx4 v = (fx4)(0.f);
    if (t >= start && t <= end) v = Sp4[p * 40000 + off];
    __builtin_nontemporal_store(v, &out4[m * 40000 + off]);
}

// ---------------- Kernel B: enc + r_Cs + c + o fused (one block per m) -----
__global__ __launch_bounds__(256) void encrco_kernel(const float* __restrict__ Sp,
                                                     const int* __restrict__ spans,
                                                     const int* __restrict__ passages,
                                                     const float* __restrict__ Wb,
                                                     const float* __restrict__ We,
                                                     const float* __restrict__ Wc,
                                                     const float* __restrict__ Wo,
                                                     float* __restrict__ enc,
                                                     float* __restrict__ r_out,
                                                     float* __restrict__ c_ws,
                                                     float* __restrict__ o_ws) {
    __shared__ float4 sb4[50], se4[50], rs4[25];
    int m = blockIdx.x;
    int p = m >> 1, k = m & 1;
    int start = spans[p * 4 + k * 2];
    int end   = spans[p * 4 + k * 2 + 1];
    int tid = threadIdx.x;

    // encoded_candidates (ints exact in f32)
    int len = end - start;
    for (int t = tid; t < LP; t += 256) {
        int g = start + t; if (g > LP - 1) g = LP - 1;
        enc[m * LP + t] = (t <= len) ? (float)passages[p * LP + g] : 0.f;
    }

    // stage sb/se rows (16B-aligned: row stride 800 B)
    const float4* sbp = (const float4*)(Sp + (size_t)(p * LP + start) * DP);
    const float4* sep = (const float4*)(Sp + (size_t)(p * LP + end) * DP);
    if (tid < 50)       sb4[tid]      = sbp[tid];
    else if (tid < 100) se4[tid - 50] = sep[tid - 50];
    __syncthreads();

    int h = tid;
    if (h < HP) {
        const float4* wb = (const float4*)(Wb + h * DP);
        const float4* we = (const float4*)(We + h * DP);
        float acc = 0.f;
        #pragma unroll
        for (int d = 0; d < 50; ++d) {
            float4 a = sb4[d], b = wb[d];
            acc += a.x * b.x + a.y * b.y + a.z * b.z + a.w * b.w;
            float4 a2 = se4[d], b2 = we[d];
            acc += a2.x * b2.x + a2.y * b2.y + a2.z * b2.z + a2.w * b2.w;
        }
        float r = tanh_fast(acc);
        ((float*)rs4)[h] = r;
        r_out[m * HP + h] = r;
    }
    __syncthreads();
    if (h < HP) {
        const float4* wc = (const float4*)(Wc + h * HP);
        const float4* wo = (const float4*)(Wo + h * HP);
        float accc = 0.f, acco = 0.f;
        #pragma unroll
        for (int q = 0; q < 25; ++q) {
            float4 r = rs4[q], cc = wc[q], oo = wo[q];
            accc += r.x * cc.x + r.y * cc.y + r.z * cc.z + r.w * cc.w;
            acco += r.x * oo.x + r.y * oo.y + r.z * oo.z + r.w * oo.w;
        }
        c_ws[m * HP + h] = accc;
        o_ws[m * HP + h] = acco;
    }
}

// ---------------- Kernel C: V (diag removed) + E ----------------
__global__ __launch_bounds__(256) void v_kernel(const float* __restrict__ c_ws,
                                                const float* __restrict__ o_ws,
                                                const float* __restrict__ Wv,
                                                float* __restrict__ V_out,
                                                float* __restrict__ E_ws) {
    __shared__ float4 cs4[25], wv4[25];
    int i = blockIdx.x;
    int tid = threadIdx.x;
    if (tid < 25) {
        cs4[tid] = ((const float4*)(c_ws + i * HP))[tid];
        wv4[tid] = ((const float4*)Wv)[tid];
    }
    __syncthreads();
    int jp = tid;
    if (jp < MM1) {
        int j = jp + (jp >= i ? 1 : 0);
        const float4* oj = (const float4*)(o_ws + j * HP);
        float acc = 0.f;
        #pragma unroll
        for (int q = 0; q < 25; ++q) {
            float4 o4 = oj[q], c4 = cs4[q], w4 = wv4[q];
            acc += tanh_fast(c4.x + o4.x) * w4.x;
            acc += tanh_fast(c4.y + o4.y) * w4.y;
            acc += tanh_fast(c4.z + o4.z) * w4.z;
            acc += tanh_fast(c4.w + o4.w) * w4.w;
        }
        V_out[i * MM1 + jp] = acc;
        E_ws[i * MM1 + jp] = __expf(acc);
    }
}

// ---------------- Kernel D: per-column colE -> alpha -> s_rows -------------
// one block per column jp (255 blocks), thread i in [0,256)
__global__ __launch_bounds__(256) void alpha_kernel(const float* __restrict__ E_ws,
                                                    float* __restrict__ s_ws) {
    __shared__ float partial[4];
    int jp = blockIdx.x;
    int i = threadIdx.x;
    float e = E_ws[i * MM1 + jp];

    // block sum of e (deterministic)
    float v = e;
    v += __shfl_down(v, 32); v += __shfl_down(v, 16); v += __shfl_down(v, 8);
    v += __shfl_down(v, 4);  v += __shfl_down(v, 2);  v += __shfl_down(v, 1);
    if ((i & 63) == 0) partial[i >> 6] = v;
    __syncthreads();
    float colE = partial[0] + partial[1] + partial[2] + partial[3];

    float a = e / (colE - e);

    __syncthreads();
    float v2 = a;
    v2 += __shfl_down(v2, 32); v2 += __shfl_down(v2, 16); v2 += __shfl_down(v2, 8);
    v2 += __shfl_down(v2, 4);  v2 += __shfl_down(v2, 2);  v2 += __shfl_down(v2, 1);
    if ((i & 63) == 0) partial[i >> 6] = v2;
    __syncthreads();
    float colA = partial[0] + partial[1] + partial[2] + partial[3];

    s_ws[i * MM1 + jp] = colA - a;   // strided store, L2-resident (261 KB)
}

// ---------------- Kernel E: tilda_r_Cs ----------------
__global__ __launch_bounds__(128) void tilda_kernel(const float* __restrict__ s_ws,
                                                    const float* __restrict__ r_out,
                                                    float* __restrict__ til_out) {
    __shared__ float s[MM1 + 1];
    int i = blockIdx.x;
    for (int jp = threadIdx.x; jp < MM1; jp += 128)
        s[jp] = s_ws[i * MM1 + jp];
    __syncthreads();
    int h = threadIdx.x;
    if (h < HP) {
        float acc = 0.f;
        #pragma unroll 4
        for (int jp = 0; jp < i; ++jp)
            acc += s[jp] * r_out[jp * HP + h];
        #pragma unroll 4
        for (int jp = i; jp < MM1; ++jp)
            acc += s[jp] * r_out[(jp + 1) * HP + h];
        til_out[i * HP + h] = acc;
    }
}

extern "C" void kernel_launch(void* const* d_in, const int* in_sizes, int n_in,
                              void* d_out, int out_size, void* d_ws, size_t ws_size,
                              hipStream_t stream) {
    const float* S_p      = (const float*)d_in[0];
    const int*   spans    = (const int*)d_in[1];
    const int*   passages = (const int*)d_in[2];
    const float* Wb       = (const float*)d_in[3];
    const float* We       = (const float*)d_in[4];
    const float* Wc       = (const float*)d_in[5];
    const float* Wo       = (const float*)d_in[6];
    const float* Wv       = (const float*)d_in[7];

    float* out = (float*)d_out;
    float* ws  = (float*)d_ws;

    float* out_scs = out + OFF_SCS;
    float* out_r   = out + OFF_R;
    float* out_enc = out + OFF_ENC;
    float* out_v   = out + OFF_V;
    float* out_til = out + OFF_TIL;

    float* ws_c = ws + WS_C;
    float* ws_o = ws + WS_O;
    float* ws_e = ws + WS_E;
    float* ws_s = ws + WS_S;

    // small chain first (independent of scs), then the big stream
    encrco_kernel<<<MP, 256, 0, stream>>>(S_p, spans, passages, Wb, We, Wc, Wo,
                                          out_enc, out_r, ws_c, ws_o);
    v_kernel<<<MP, 256, 0, stream>>>(ws_c, ws_o, Wv, out_v, ws_e);
    alpha_kernel<<<MM1, 256, 0, stream>>>(ws_e, ws_s);
    tilda_kernel<<<MP, 128, 0, stream>>>(ws_s, out_r, out_til);

    dim3 gridA((40000 + 255) / 256, MP);
    scs_kernel<<<gridA, 256, 0, stream>>>((const fx4*)S_p, spans, (fx4*)out_scs);
}